// Round 6
// baseline (147.848 us; speedup 1.0000x reference)
//
#include <hip/hip_runtime.h>
#include <math.h>

#define N_NODES 1024
#define N_EVAL 131072
#define NUM_POLES 8
#define PI_D 3.14159265358979323846

// ============================================================================
// V7: barrier-free single-wave ownership + pair-merged scalar stream.
//
// Evidence V1-V6: busy-time tracks instruction count (10-22us) but wall is
// pinned at 60-76us; per-wave lifetime (occupancy x dur / waves) is 10-22us
// in EVERY variant vs 1-4us of issue, with only ~2-5 waves/CU resident while
// blocks queue. The common structural trait of all slow variants: multi-wave
// blocks in barrier lockstep + LDS reduction + masked tail -> each wave's
// lifetime includes the block's slowest wave and the reduce; block
// retirement gates refill. V7 removes all of it:
//   - Each wave owns 64 points across ALL 512 node-pairs. No __syncthreads,
//     no LDS reduce, no masked tail. Waves retire independently.
//   - Pair merge: wv0/(x-a) + wv1/(x-b) = (sv*x+tv) * rcp((x-a)*(x-b)),
//     sv=wv0+wv1, tv=-(wv0*b+wv1*a) (and sw,tw for the denominator sum).
//     8 VALU/pair/point (2 add, 1 mul, 1 rcp, 4 fma) = same core count as
//     V2 but half the trans-pipe rcps; near-node accuracy is safe: d's are
//     computed directly (Sterbenz-exact), numerators are linear fma forms
//     (rel err ~3e-5), and rcp error cancels between num and den.
//   - Pair table = 512 x 6 floats = 12KB, wave-uniform s_load stream
//     (K$-resident), 4-pair batches, alternating accumulator sets.
//   - 1024 blocks x 128 thr (2 independent waves); 2048 waves total.
//
// d_ws layout (floats): [0,1024) nodes, [1024,2048) w, [2048,3072) w*v
// (kept for the rare exact-hit fixup), [3072,6144) pair table
// {-a,-b,sv,tv,sw,tw} per pair. Exact node hit -> q=0 -> r=inf -> NaN ->
// per-lane rescan fixup (reference: exact-hit column reduces to
// sum(hit w*v)/sum(hit w)).
//
// Weights: Chebyshev pts of the 2nd kind, 1/prod_{i!=j}(x_j-x_i) =
// (-1)^j*delta_j*2^(n-1)/n; uniform positive scalings cancel in num/den, so
// w_j = (-1)^j * delta_j * prod_m((x_j-pr_m)^2 + pi_m^2).
// ============================================================================

__global__ __launch_bounds__(256) void setup_kernel(
    const float* __restrict__ values,
    const float* __restrict__ poles_real,
    const float* __restrict__ poles_imag,
    float* __restrict__ ws) {
    const int j = blockIdx.x * 256 + threadIdx.x;
    const double nd = cos(PI_D * (double)j / (double)(N_NODES - 1));
    double prod = (j == 0 || j == N_NODES - 1) ? 0.5 : 1.0;
#pragma unroll
    for (int m = 0; m < NUM_POLES; ++m) {
        const double dr = nd - (double)poles_real[m];
        const double di = (double)poles_imag[m];
        prod *= dr * dr + di * di;
    }
    if (j & 1) prod = -prod;
    ws[j]        = (float)nd;
    ws[j + 1024] = (float)prod;
    ws[j + 2048] = (float)(prod * (double)values[j]);
}

__global__ __launch_bounds__(256) void setup_pairs_kernel(float* __restrict__ ws) {
    const int k = blockIdx.x * 256 + threadIdx.x;   // pair index 0..511
    const double a   = (double)ws[2 * k];
    const double b   = (double)ws[2 * k + 1];
    const double w0  = (double)ws[1024 + 2 * k];
    const double w1  = (double)ws[1024 + 2 * k + 1];
    const double wv0 = (double)ws[2048 + 2 * k];
    const double wv1 = (double)ws[2048 + 2 * k + 1];
    float* p = ws + 3072 + k * 6;
    p[0] = (float)(-a);
    p[1] = (float)(-b);
    p[2] = (float)(wv0 + wv1);            // sv
    p[3] = (float)(-(wv0 * b + wv1 * a)); // tv
    p[4] = (float)(w0 + w1);              // sw
    p[5] = (float)(-(w0 * b + w1 * a));   // tw
}

__global__ __launch_bounds__(128) void eval_pairs_kernel(
    const float* __restrict__ x_eval,
    const float* __restrict__ ws,
    float* __restrict__ out) {
    const int t = threadIdx.x;
    const int lane = t & 63;
    const int wid  = __builtin_amdgcn_readfirstlane(t >> 6);  // 0 or 1
    const int pbase = blockIdx.x * 128 + wid * 64;

    const float x = x_eval[pbase + lane];
    const float* __restrict__ pt = ws + 3072;

    float a0 = 0.0f, b0 = 0.0f, a1 = 0.0f, b1 = 0.0f;

#define PAIR(NA, NB, SV, TV, SW, TW, AA, BB)                                 \
    {                                                                        \
        const float d0 = x + (NA);                                           \
        const float d1 = x + (NB);                                           \
        const float q  = d0 * d1;                                            \
        const float r  = __builtin_amdgcn_rcpf(q);                           \
        const float nv = fmaf((SV), x, (TV));                                \
        const float nw = fmaf((SW), x, (TW));                                \
        AA = fmaf(nv, r, AA);                                                \
        BB = fmaf(nw, r, BB);                                                \
    }

    // 128 batches of 4 pairs; each batch = 24 wave-uniform dwords
    // (3x s_load_dwordx8) feeding 32 VALU. No memory/LDS/barrier deps.
#pragma unroll 2
    for (int k = 0; k < 512; k += 4) {
        const float* c = pt + k * 6;
        float C[24];
#pragma unroll
        for (int i = 0; i < 24; ++i) C[i] = c[i];
        PAIR(C[0],  C[1],  C[2],  C[3],  C[4],  C[5],  a0, b0)
        PAIR(C[6],  C[7],  C[8],  C[9],  C[10], C[11], a1, b1)
        PAIR(C[12], C[13], C[14], C[15], C[16], C[17], a0, b0)
        PAIR(C[18], C[19], C[20], C[21], C[22], C[23], a1, b1)
    }
#undef PAIR

    float res = (a0 + a1) / (b0 + b1);
    if (__builtin_expect(__builtin_isnan(res), 0)) {
        float hn = 0.0f, hd = 0.0f;
        for (int jj = 0; jj < N_NODES; ++jj) {
            if (ws[jj] == x) { hn += ws[2048 + jj]; hd += ws[1024 + jj]; }
        }
        res = hn / hd;
    }
    out[pbase + lane] = res;
}

// ============================================================================
// Fallback (verified round-0 kernel) if the harness workspace is too small.
// ============================================================================
__global__ __launch_bounds__(512, 4) void eval_kernel_fused(
    const float* __restrict__ x_eval,
    const float* __restrict__ values,
    const float* __restrict__ poles_real,
    const float* __restrict__ poles_imag,
    float* __restrict__ out) {
    __shared__ __align__(16) float s_n[N_NODES];
    __shared__ __align__(16) float s_w[N_NODES];
    __shared__ __align__(16) float s_v[N_NODES];
    __shared__ float2 s_r[8][256];

    const int t = threadIdx.x;

#pragma unroll
    for (int h = 0; h < 2; ++h) {
        const int j = t + h * 512;
        const double nd = cos(PI_D * (double)j / (double)(N_NODES - 1));
        double prod = (j == 0 || j == N_NODES - 1) ? 0.5 : 1.0;
#pragma unroll
        for (int m = 0; m < NUM_POLES; ++m) {
            const double dr = nd - (double)poles_real[m];
            const double di = (double)poles_imag[m];
            prod *= dr * dr + di * di;
        }
        if (j & 1) prod = -prod;
        s_n[j] = (float)nd;
        s_w[j] = (float)prod;
        s_v[j] = (float)(prod * (double)values[j]);
    }
    __syncthreads();

    const int lane = t & 63;
    const int wid  = t >> 6;
    const int pbase = blockIdx.x * 256;
    const float x0 = x_eval[pbase + lane];
    const float x1 = x_eval[pbase + 64 + lane];
    const float x2 = x_eval[pbase + 128 + lane];
    const float x3 = x_eval[pbase + 192 + lane];

    const float4* n4 = (const float4*)s_n + wid * 32;
    const float4* w4 = (const float4*)s_w + wid * 32;
    const float4* v4 = (const float4*)s_v + wid * 32;

    float a0 = 0.0f, b0 = 0.0f, a1 = 0.0f, b1 = 0.0f;
    float a2 = 0.0f, b2 = 0.0f, a3 = 0.0f, b3 = 0.0f;

#define NODE(C)                                                            \
    {                                                                      \
        const float d0 = x0 - an.C;                                        \
        const float d1 = x1 - an.C;                                        \
        const float d2 = x2 - an.C;                                        \
        const float d3 = x3 - an.C;                                        \
        const float r0 = __builtin_amdgcn_rcpf(d0);                        \
        const float r1 = __builtin_amdgcn_rcpf(d1);                        \
        const float r2 = __builtin_amdgcn_rcpf(d2);                        \
        const float r3 = __builtin_amdgcn_rcpf(d3);                        \
        a0 = fmaf(av.C, r0, a0); b0 = fmaf(aw.C, r0, b0);                  \
        a1 = fmaf(av.C, r1, a1); b1 = fmaf(aw.C, r1, b1);                  \
        a2 = fmaf(av.C, r2, a2); b2 = fmaf(aw.C, r2, b2);                  \
        a3 = fmaf(av.C, r3, a3); b3 = fmaf(aw.C, r3, b3);                  \
    }

#pragma unroll 4
    for (int q = 0; q < 32; ++q) {
        const float4 an = n4[q];
        const float4 aw = w4[q];
        const float4 av = v4[q];
        NODE(x) NODE(y) NODE(z) NODE(w)
    }
#undef NODE

    s_r[wid][lane]       = make_float2(a0, b0);
    s_r[wid][lane + 64]  = make_float2(a1, b1);
    s_r[wid][lane + 128] = make_float2(a2, b2);
    s_r[wid][lane + 192] = make_float2(a3, b3);
    __syncthreads();

    if (t < 256) {
        float nn = 0.0f, dd = 0.0f;
#pragma unroll
        for (int w = 0; w < 8; ++w) {
            const float2 pr = s_r[w][t];
            nn += pr.x;
            dd += pr.y;
        }
        float res = nn / dd;
        if (__builtin_expect(__builtin_isnan(res), 0)) {
            const float x = x_eval[pbase + t];
            float hn = 0.0f, hd = 0.0f;
            for (int j = 0; j < N_NODES; ++j) {
                if (s_n[j] == x) { hn += s_v[j]; hd += s_w[j]; }
            }
            res = hn / hd;
        }
        out[pbase + t] = res;
    }
}

extern "C" void kernel_launch(void* const* d_in, const int* in_sizes, int n_in,
                              void* d_out, int out_size, void* d_ws, size_t ws_size,
                              hipStream_t stream) {
    const float* x_eval     = (const float*)d_in[0];
    const float* values     = (const float*)d_in[1];
    const float* poles_real = (const float*)d_in[2];
    const float* poles_imag = (const float*)d_in[3];
    float* out = (float*)d_out;

    if (ws_size >= 6144 * sizeof(float)) {
        float* ws = (float*)d_ws;
        setup_kernel<<<N_NODES / 256, 256, 0, stream>>>(values, poles_real,
                                                        poles_imag, ws);
        setup_pairs_kernel<<<2, 256, 0, stream>>>(ws);
        eval_pairs_kernel<<<N_EVAL / 128, 128, 0, stream>>>(x_eval, ws, out);
    } else {
        eval_kernel_fused<<<N_EVAL / 256, 512, 0, stream>>>(
            x_eval, values, poles_real, poles_imag, out);
    }
}

// Round 7
// 133.695 us; speedup vs baseline: 1.1059x; 1.1059x over previous
//
#include <hip/hip_runtime.h>
#include <math.h>

#define N_NODES 1024
#define N_EVAL 131072
#define NUM_POLES 8
#define PI_D 3.14159265358979323846

typedef float v2f __attribute__((ext_vector_type(2)));

static __device__ __forceinline__ v2f splat2(float s) {
    v2f r; r.x = s; r.y = s; return r;
}

// ============================================================================
// V8: packed-FP32 (VOP3P) pair math + V2's proven scalar-stream idiom.
//
// Model from V1-V7: wall time fits a VALU-issue-bound model at ~128 SIMDs
// (V2 4 inst/node-pt -> 65us pred / 60 meas; V3 65/61.8; V4 70/71; V5
// 75/75.8), while the 1024-SIMD model is 8-9x off for every variant. The
// two outliers (V6, V7) are exactly the two whose uniform-table loads
// de-scalarized (V6 FETCH 318->482KB; V7 local-array copy). Lever: cut
// instructions per node-point, keeping V2's direct-indexed SoA loads
// (the only pattern proven to scalarize: SGPR=80, FETCH~320KB).
//
// Math (per pair k, per 2 points packed in v2f X):
//   wv0/(x-a)+wv1/(x-b) = (sv*x+tv) * r,  r = rcp((x-a)*(x-b))
// reassociated as  sv*(x*r) + tv*r  so every pk_fma has exactly ONE scalar
// operand (1-SGPR-per-VALU rule, no per-pair v_movs), accumulated in split
// sums (Asv,Atv / Bsw,Btw). 10 inst per pair per 2 points = 2.5/node-pt
// vs V2's 4.0. Near-node: d's are direct subtractions (Sterbenz-exact);
// split-sum cancellation occurs only where num/den are themselves ~1/d
// large, so relative error stays ~3e-5 (V7's identical pair math passed).
//
// d_ws layout (floats): [0,1024) nodes, [1024,2048) w, [2048,3072) w*v
// (kept for the rare exact-hit fixup), then SoA pair tables of 512 each:
// [3072) na=-a, [3584) nb=-b, [4096) sv, [4608) tv, [5120) sw, [5632) tw.
//
// Weights: Chebyshev pts of the 2nd kind, 1/prod_{i!=j}(x_j-x_i) =
// (-1)^j*delta_j*2^(n-1)/n; uniform positive scalings cancel in num/den, so
// w_j = (-1)^j * delta_j * prod_m((x_j-pr_m)^2 + pi_m^2).
// Exact node hit -> q=0 -> r=inf -> NaN -> per-lane rescan fixup
// (reference: exact-hit column reduces to sum(hit w*v)/sum(hit w)).
// ============================================================================

__global__ __launch_bounds__(256) void setup_kernel(
    const float* __restrict__ values,
    const float* __restrict__ poles_real,
    const float* __restrict__ poles_imag,
    float* __restrict__ ws) {
    const int j = blockIdx.x * 256 + threadIdx.x;
    const double nd = cos(PI_D * (double)j / (double)(N_NODES - 1));
    double prod = (j == 0 || j == N_NODES - 1) ? 0.5 : 1.0;
#pragma unroll
    for (int m = 0; m < NUM_POLES; ++m) {
        const double dr = nd - (double)poles_real[m];
        const double di = (double)poles_imag[m];
        prod *= dr * dr + di * di;
    }
    if (j & 1) prod = -prod;
    ws[j]        = (float)nd;
    ws[j + 1024] = (float)prod;
    ws[j + 2048] = (float)(prod * (double)values[j]);
}

__global__ __launch_bounds__(256) void setup_pairs_kernel(float* __restrict__ ws) {
    const int k = blockIdx.x * 256 + threadIdx.x;   // pair index 0..511
    const double a   = (double)ws[2 * k];
    const double b   = (double)ws[2 * k + 1];
    const double w0  = (double)ws[1024 + 2 * k];
    const double w1  = (double)ws[1024 + 2 * k + 1];
    const double wv0 = (double)ws[2048 + 2 * k];
    const double wv1 = (double)ws[2048 + 2 * k + 1];
    ws[3072 + k] = (float)(-a);
    ws[3584 + k] = (float)(-b);
    ws[4096 + k] = (float)(wv0 + wv1);            // sv
    ws[4608 + k] = (float)(-(wv0 * b + wv1 * a)); // tv
    ws[5120 + k] = (float)(w0 + w1);              // sw
    ws[5632 + k] = (float)(-(w0 * b + w1 * a));   // tw
}

__global__ __launch_bounds__(256) void eval_pk2_kernel(
    const float* __restrict__ x_eval,
    const float* __restrict__ ws,
    float* __restrict__ out) {
    __shared__ float2 s_rA[4][64];   // partials for points [0,64)
    __shared__ float2 s_rB[4][64];   // partials for points [64,128)

    const int t = threadIdx.x;
    const int lane = t & 63;
    // Wave-uniform so the six table streams scalarize (s_load).
    const int wid = __builtin_amdgcn_readfirstlane(t >> 6);   // 0..3
    const int pbase = blockIdx.x * 128;

    v2f X;
    X.x = x_eval[pbase + lane];
    X.y = x_eval[pbase + 64 + lane];

    // This wave's 128 pairs, six scalar SoA streams (V2's proven idiom:
    // direct indexed reads off __restrict__ base pointers).
    const float* __restrict__ pna = ws + 3072 + wid * 128;
    const float* __restrict__ pnb = ws + 3584 + wid * 128;
    const float* __restrict__ psv = ws + 4096 + wid * 128;
    const float* __restrict__ ptv = ws + 4608 + wid * 128;
    const float* __restrict__ psw = ws + 5120 + wid * 128;
    const float* __restrict__ ptw = ws + 5632 + wid * 128;

    v2f Asv0 = {0.0f, 0.0f}, Atv0 = {0.0f, 0.0f};
    v2f Bsw0 = {0.0f, 0.0f}, Btw0 = {0.0f, 0.0f};
    v2f Asv1 = {0.0f, 0.0f}, Atv1 = {0.0f, 0.0f};
    v2f Bsw1 = {0.0f, 0.0f}, Btw1 = {0.0f, 0.0f};

#define PAIR(K, ASV, ATV, BSW, BTW)                                          \
    {                                                                        \
        const float na = pna[K];                                             \
        const float nb = pnb[K];                                             \
        const float sv = psv[K];                                             \
        const float tv = ptv[K];                                             \
        const float sw = psw[K];                                             \
        const float tw = ptw[K];                                             \
        const v2f D0 = X + splat2(na);       /* pk_add, sgpr broadcast */    \
        const v2f D1 = X + splat2(nb);                                       \
        const v2f Q  = D0 * D1;              /* pk_mul */                    \
        v2f R;                                                               \
        R.x = __builtin_amdgcn_rcpf(Q.x);                                    \
        R.y = __builtin_amdgcn_rcpf(Q.y);                                    \
        const v2f XR = X * R;                                                \
        ASV = __builtin_elementwise_fma(splat2(sv), XR, ASV);                \
        ATV = __builtin_elementwise_fma(splat2(tv), R,  ATV);                \
        BSW = __builtin_elementwise_fma(splat2(sw), XR, BSW);                \
        BTW = __builtin_elementwise_fma(splat2(tw), R,  BTW);                \
    }

    // 32 batches of 4 pairs; 24 wave-uniform dwords per batch feeding
    // 40 VALU. Alternating accumulator banks for ILP.
#pragma unroll 2
    for (int k = 0; k < 128; k += 4) {
        PAIR(k,     Asv0, Atv0, Bsw0, Btw0)
        PAIR(k + 1, Asv1, Atv1, Bsw1, Btw1)
        PAIR(k + 2, Asv0, Atv0, Bsw0, Btw0)
        PAIR(k + 3, Asv1, Atv1, Bsw1, Btw1)
    }
#undef PAIR

    const v2f A = (Asv0 + Asv1) + (Atv0 + Atv1);
    const v2f B = (Bsw0 + Bsw1) + (Btw0 + Btw1);
    s_rA[wid][lane] = make_float2(A.x, B.x);
    s_rB[wid][lane] = make_float2(A.y, B.y);
    __syncthreads();

    if (t < 128) {
        const int half = t >> 6;          // 0: points [0,64), 1: [64,128)
        const int idx  = t & 63;
        float num = 0.0f, den = 0.0f;
#pragma unroll
        for (int w = 0; w < 4; ++w) {
            const float2 p = half ? s_rB[w][idx] : s_rA[w][idx];
            num += p.x;
            den += p.y;
        }
        float res = num / den;
        if (__builtin_expect(__builtin_isnan(res), 0)) {
            const float xv = x_eval[pbase + t];
            float hn = 0.0f, hd = 0.0f;
            for (int jj = 0; jj < N_NODES; ++jj) {
                if (ws[jj] == xv) { hn += ws[2048 + jj]; hd += ws[1024 + jj]; }
            }
            res = hn / hd;
        }
        out[pbase + t] = res;
    }
}

// ============================================================================
// Fallback (verified round-0 kernel) if the harness workspace is too small.
// ============================================================================
__global__ __launch_bounds__(512, 4) void eval_kernel_fused(
    const float* __restrict__ x_eval,
    const float* __restrict__ values,
    const float* __restrict__ poles_real,
    const float* __restrict__ poles_imag,
    float* __restrict__ out) {
    __shared__ __align__(16) float s_n[N_NODES];
    __shared__ __align__(16) float s_w[N_NODES];
    __shared__ __align__(16) float s_v[N_NODES];
    __shared__ float2 s_r[8][256];

    const int t = threadIdx.x;

#pragma unroll
    for (int h = 0; h < 2; ++h) {
        const int j = t + h * 512;
        const double nd = cos(PI_D * (double)j / (double)(N_NODES - 1));
        double prod = (j == 0 || j == N_NODES - 1) ? 0.5 : 1.0;
#pragma unroll
        for (int m = 0; m < NUM_POLES; ++m) {
            const double dr = nd - (double)poles_real[m];
            const double di = (double)poles_imag[m];
            prod *= dr * dr + di * di;
        }
        if (j & 1) prod = -prod;
        s_n[j] = (float)nd;
        s_w[j] = (float)prod;
        s_v[j] = (float)(prod * (double)values[j]);
    }
    __syncthreads();

    const int lane = t & 63;
    const int wid  = t >> 6;
    const int pbase = blockIdx.x * 256;
    const float x0 = x_eval[pbase + lane];
    const float x1 = x_eval[pbase + 64 + lane];
    const float x2 = x_eval[pbase + 128 + lane];
    const float x3 = x_eval[pbase + 192 + lane];

    const float4* n4 = (const float4*)s_n + wid * 32;
    const float4* w4 = (const float4*)s_w + wid * 32;
    const float4* v4 = (const float4*)s_v + wid * 32;

    float a0 = 0.0f, b0 = 0.0f, a1 = 0.0f, b1 = 0.0f;
    float a2 = 0.0f, b2 = 0.0f, a3 = 0.0f, b3 = 0.0f;

#define NODE(C)                                                            \
    {                                                                      \
        const float d0 = x0 - an.C;                                        \
        const float d1 = x1 - an.C;                                        \
        const float d2 = x2 - an.C;                                        \
        const float d3 = x3 - an.C;                                        \
        const float r0 = __builtin_amdgcn_rcpf(d0);                        \
        const float r1 = __builtin_amdgcn_rcpf(d1);                        \
        const float r2 = __builtin_amdgcn_rcpf(d2);                        \
        const float r3 = __builtin_amdgcn_rcpf(d3);                        \
        a0 = fmaf(av.C, r0, a0); b0 = fmaf(aw.C, r0, b0);                  \
        a1 = fmaf(av.C, r1, a1); b1 = fmaf(aw.C, r1, b1);                  \
        a2 = fmaf(av.C, r2, a2); b2 = fmaf(aw.C, r2, b2);                  \
        a3 = fmaf(av.C, r3, a3); b3 = fmaf(aw.C, r3, b3);                  \
    }

#pragma unroll 4
    for (int q = 0; q < 32; ++q) {
        const float4 an = n4[q];
        const float4 aw = w4[q];
        const float4 av = v4[q];
        NODE(x) NODE(y) NODE(z) NODE(w)
    }
#undef NODE

    s_r[wid][lane]       = make_float2(a0, b0);
    s_r[wid][lane + 64]  = make_float2(a1, b1);
    s_r[wid][lane + 128] = make_float2(a2, b2);
    s_r[wid][lane + 192] = make_float2(a3, b3);
    __syncthreads();

    if (t < 256) {
        float nn = 0.0f, dd = 0.0f;
#pragma unroll
        for (int w = 0; w < 8; ++w) {
            const float2 pr = s_r[w][t];
            nn += pr.x;
            dd += pr.y;
        }
        float res = nn / dd;
        if (__builtin_expect(__builtin_isnan(res), 0)) {
            const float x = x_eval[pbase + t];
            float hn = 0.0f, hd = 0.0f;
            for (int j = 0; j < N_NODES; ++j) {
                if (s_n[j] == x) { hn += s_v[j]; hd += s_w[j]; }
            }
            res = hn / hd;
        }
        out[pbase + t] = res;
    }
}

extern "C" void kernel_launch(void* const* d_in, const int* in_sizes, int n_in,
                              void* d_out, int out_size, void* d_ws, size_t ws_size,
                              hipStream_t stream) {
    const float* x_eval     = (const float*)d_in[0];
    const float* values     = (const float*)d_in[1];
    const float* poles_real = (const float*)d_in[2];
    const float* poles_imag = (const float*)d_in[3];
    float* out = (float*)d_out;

    if (ws_size >= 6144 * sizeof(float)) {
        float* ws = (float*)d_ws;
        setup_kernel<<<N_NODES / 256, 256, 0, stream>>>(values, poles_real,
                                                        poles_imag, ws);
        setup_pairs_kernel<<<2, 256, 0, stream>>>(ws);
        eval_pk2_kernel<<<N_EVAL / 128, 256, 0, stream>>>(x_eval, ws, out);
    } else {
        eval_kernel_fused<<<N_EVAL / 256, 512, 0, stream>>>(
            x_eval, values, poles_real, poles_imag, out);
    }
}

// Round 8
// 116.410 us; speedup vs baseline: 1.2701x; 1.1485x over previous
//
#include <hip/hip_runtime.h>
#include <math.h>

#define N_NODES 1024
#define N_EVAL 131072
#define NUM_POLES 8
#define PI_D 3.14159265358979323846

// ============================================================================
// FINAL (pinned): V2 — two-kernel design, scalar node stream, 1 point/thread.
// Best measured of 8 structural variants (kernel 60.0us, bench 116.4us,
// absmax 0.0156).
//
// Session findings (V1-V8, all falsified attempts to beat this):
//  - LDS-broadcast staging (V1/round-0): 73.5us — exposed lgkmcnt per batch.
//  - scalar-stream x4 pts/thread (V3): 61.8us — tie; amortization no help.
//  - register-systolic shuffle ring (V4): 71us — compiler spilled the node
//    arrays (VGPR=32 < 48 needed); 5 ds_bpermute/step loaded the LDS pipe.
//  - readlane broadcast (V5): 75.8us — same spill failure (VGPR=24).
//  - pair-merge + packed fp32 (V6/V8): 75.5-76us — v_pk_*_f32 gives NO
//    throughput vs scalar f32 on gfx950 (sequenced half-rate; density only),
//    and cutting inst/node-pt 4.0 -> 2.5 did not move wall. absmax worsened
//    to 0.0234 (split-sum reassociation).
//  - barrier-free single-wave ownership (V7): 89us — de-scalarized loads.
// Invariant: wall 60-90us with VALU busy-time 9.6-22us, occupancy <=16%
// despite 8192 queued waves, HBM 0.15% peak, zero bank conflicts. The ~5x
// busy-vs-wall gap never moved under any structural change; no counter
// identifies the stall. Per pre-committed decision rule, exploration stops
// and the empirical best is pinned.
//
// Design:
//  - setup_kernel: closed-form barycentric weights (fp64, computed ONCE).
//    For Chebyshev pts of the 2nd kind, 1/prod_{i!=j}(x_j-x_i) =
//    (-1)^j*delta_j*2^(n-1)/n; uniform positive scalings cancel in num/den,
//    so w_j = (-1)^j * delta_j * prod_m((x_j-pr_m)^2 + pi_m^2).
//    ws[0..1024)=nodes, [1024..2048)=w, [2048..3072)=w*v.
//  - eval_scalar_kernel: 2048 blocks x 256 thr. Wave w handles nodes
//    [w*256, w*256+256) for the block's 64 points (1/thread). Node/w/v
//    loads are wave-uniform (wid via readfirstlane) -> s_load into SGPRs
//    (SGPR=80 confirms); inner loop is pure VALU: v_sub, v_rcp, 2x v_fma
//    with one SGPR operand each. No LDS/barrier/lgkmcnt dep in hot loop.
//    4 wave-partials per point reduced via 2KB LDS; rare exact-hit NaN
//    fixup (reference: exact-hit column reduces to sum(hit w*v)/sum(hit w)).
// ============================================================================

__global__ __launch_bounds__(256) void setup_kernel(
    const float* __restrict__ values,
    const float* __restrict__ poles_real,
    const float* __restrict__ poles_imag,
    float* __restrict__ ws) {
    const int j = blockIdx.x * 256 + threadIdx.x;
    // Chebyshev node (2nd kind), fp64 for node accuracy near the ends.
    const double nd = cos(PI_D * (double)j / (double)(N_NODES - 1));
    double prod = (j == 0 || j == N_NODES - 1) ? 0.5 : 1.0;
#pragma unroll
    for (int m = 0; m < NUM_POLES; ++m) {
        const double dr = nd - (double)poles_real[m];
        const double di = (double)poles_imag[m];
        prod *= dr * dr + di * di;
    }
    if (j & 1) prod = -prod;
    ws[j]        = (float)nd;
    ws[j + 1024] = (float)prod;
    ws[j + 2048] = (float)(prod * (double)values[j]);
}

__global__ __launch_bounds__(256, 8) void eval_scalar_kernel(
    const float* __restrict__ x_eval,
    const float* __restrict__ ws,
    float* __restrict__ out) {
    __shared__ float2 s_red[4][64];

    const int t = threadIdx.x;
    const int lane = t & 63;
    // Force wave-uniformity so the node-stream addresses scalarize (s_load).
    const int wid = __builtin_amdgcn_readfirstlane(t >> 6);
    const int pbase = blockIdx.x * 64;

    const float x = x_eval[pbase + lane];

    const float* __restrict__ nn = ws + wid * 256;
    const float* __restrict__ wq = ws + 1024 + wid * 256;
    const float* __restrict__ vq = ws + 2048 + wid * 256;

    // Two independent accumulator chains per (num,den) for FMA-latency cover.
    float a0 = 0.0f, b0 = 0.0f, a1 = 0.0f, b1 = 0.0f;

#pragma unroll 2
    for (int j = 0; j < 256; j += 8) {
#pragma unroll
        for (int k = 0; k < 8; k += 2) {
            const float n0 = nn[j + k];
            const float w0 = wq[j + k];
            const float v0 = vq[j + k];
            const float n1 = nn[j + k + 1];
            const float w1 = wq[j + k + 1];
            const float v1 = vq[j + k + 1];
            const float d0 = x - n0;
            const float d1 = x - n1;
            const float r0 = __builtin_amdgcn_rcpf(d0);
            const float r1 = __builtin_amdgcn_rcpf(d1);
            a0 = fmaf(v0, r0, a0);
            b0 = fmaf(w0, r0, b0);
            a1 = fmaf(v1, r1, a1);
            b1 = fmaf(w1, r1, b1);
        }
    }

    s_red[wid][lane] = make_float2(a0 + a1, b0 + b1);
    __syncthreads();

    if (t < 64) {
        float num = 0.0f, den = 0.0f;
#pragma unroll
        for (int w = 0; w < 4; ++w) {
            const float2 p = s_red[w][t];
            num += p.x;
            den += p.y;
        }
        float res = num / den;
        if (__builtin_expect(__builtin_isnan(res), 0)) {
            const float xx = x_eval[pbase + t];
            float hn = 0.0f, hd = 0.0f;
            for (int jj = 0; jj < N_NODES; ++jj) {
                if (ws[jj] == xx) { hn += ws[2048 + jj]; hd += ws[1024 + jj]; }
            }
            res = hn / hd;
        }
        out[pbase + t] = res;
    }
}

// ============================================================================
// Fallback (verified round-0 kernel) if the harness workspace is too small.
// ============================================================================
__global__ __launch_bounds__(512, 4) void eval_kernel_fused(
    const float* __restrict__ x_eval,
    const float* __restrict__ values,
    const float* __restrict__ poles_real,
    const float* __restrict__ poles_imag,
    float* __restrict__ out) {
    __shared__ __align__(16) float s_n[N_NODES];
    __shared__ __align__(16) float s_w[N_NODES];
    __shared__ __align__(16) float s_v[N_NODES];
    __shared__ float2 s_r[8][256];

    const int t = threadIdx.x;

#pragma unroll
    for (int h = 0; h < 2; ++h) {
        const int j = t + h * 512;
        const double nd = cos(PI_D * (double)j / (double)(N_NODES - 1));
        double prod = (j == 0 || j == N_NODES - 1) ? 0.5 : 1.0;
#pragma unroll
        for (int m = 0; m < NUM_POLES; ++m) {
            const double dr = nd - (double)poles_real[m];
            const double di = (double)poles_imag[m];
            prod *= dr * dr + di * di;
        }
        if (j & 1) prod = -prod;
        s_n[j] = (float)nd;
        s_w[j] = (float)prod;
        s_v[j] = (float)(prod * (double)values[j]);
    }
    __syncthreads();

    const int lane = t & 63;
    const int wid  = t >> 6;
    const int pbase = blockIdx.x * 256;
    const float x0 = x_eval[pbase + lane];
    const float x1 = x_eval[pbase + 64 + lane];
    const float x2 = x_eval[pbase + 128 + lane];
    const float x3 = x_eval[pbase + 192 + lane];

    const float4* n4 = (const float4*)s_n + wid * 32;
    const float4* w4 = (const float4*)s_w + wid * 32;
    const float4* v4 = (const float4*)s_v + wid * 32;

    float a0 = 0.0f, b0 = 0.0f, a1 = 0.0f, b1 = 0.0f;
    float a2 = 0.0f, b2 = 0.0f, a3 = 0.0f, b3 = 0.0f;

#define NODE(C)                                                            \
    {                                                                      \
        const float d0 = x0 - an.C;                                        \
        const float d1 = x1 - an.C;                                        \
        const float d2 = x2 - an.C;                                        \
        const float d3 = x3 - an.C;                                        \
        const float r0 = __builtin_amdgcn_rcpf(d0);                        \
        const float r1 = __builtin_amdgcn_rcpf(d1);                        \
        const float r2 = __builtin_amdgcn_rcpf(d2);                        \
        const float r3 = __builtin_amdgcn_rcpf(d3);                        \
        a0 = fmaf(av.C, r0, a0); b0 = fmaf(aw.C, r0, b0);                  \
        a1 = fmaf(av.C, r1, a1); b1 = fmaf(aw.C, r1, b1);                  \
        a2 = fmaf(av.C, r2, a2); b2 = fmaf(aw.C, r2, b2);                  \
        a3 = fmaf(av.C, r3, a3); b3 = fmaf(aw.C, r3, b3);                  \
    }

#pragma unroll 4
    for (int q = 0; q < 32; ++q) {
        const float4 an = n4[q];
        const float4 aw = w4[q];
        const float4 av = v4[q];
        NODE(x) NODE(y) NODE(z) NODE(w)
    }
#undef NODE

    s_r[wid][lane]       = make_float2(a0, b0);
    s_r[wid][lane + 64]  = make_float2(a1, b1);
    s_r[wid][lane + 128] = make_float2(a2, b2);
    s_r[wid][lane + 192] = make_float2(a3, b3);
    __syncthreads();

    if (t < 256) {
        float nn = 0.0f, dd = 0.0f;
#pragma unroll
        for (int w = 0; w < 8; ++w) {
            const float2 pr = s_r[w][t];
            nn += pr.x;
            dd += pr.y;
        }
        float res = nn / dd;
        if (__builtin_expect(__builtin_isnan(res), 0)) {
            const float x = x_eval[pbase + t];
            float hn = 0.0f, hd = 0.0f;
            for (int j = 0; j < N_NODES; ++j) {
                if (s_n[j] == x) { hn += s_v[j]; hd += s_w[j]; }
            }
            res = hn / hd;
        }
        out[pbase + t] = res;
    }
}

extern "C" void kernel_launch(void* const* d_in, const int* in_sizes, int n_in,
                              void* d_out, int out_size, void* d_ws, size_t ws_size,
                              hipStream_t stream) {
    const float* x_eval     = (const float*)d_in[0];
    const float* values     = (const float*)d_in[1];
    const float* poles_real = (const float*)d_in[2];
    const float* poles_imag = (const float*)d_in[3];
    float* out = (float*)d_out;

    if (ws_size >= 3 * N_NODES * sizeof(float)) {
        float* ws = (float*)d_ws;
        setup_kernel<<<N_NODES / 256, 256, 0, stream>>>(values, poles_real,
                                                        poles_imag, ws);
        eval_scalar_kernel<<<N_EVAL / 64, 256, 0, stream>>>(x_eval, ws, out);
    } else {
        eval_kernel_fused<<<N_EVAL / 256, 512, 0, stream>>>(
            x_eval, values, poles_real, poles_imag, out);
    }
}